// Round 7
// baseline (63.455 us; speedup 1.0000x reference)
//
#include <hip/hip_runtime.h>

#define NN 8
#define MM 8
#define NH1 64
#define NH2 32

#define FOR8(OP) OP(0) OP(1) OP(2) OP(3) OP(4) OP(5) OP(6) OP(7)

typedef float v2f __attribute__((ext_vector_type(2)));

// LDS layout (floats)
#define OFF_W1   0        // 512
#define OFF_W21  512      // 2048
#define OFF_W22  2560     // 2048
#define OFF_W31  4608     // 256
#define OFF_W32  4864     // 32
#define OFF_B1   4896     // 64
#define OFF_B21  4960     // 32
#define OFF_B22  4992     // 32
#define OFF_B31  5024     // 8
#define OFF_A    5032     // 64
#define OFF_G    5096     // 64
#define OFF_MEAN 5160     // 8
#define OFF_STD  5168     // 8
#define OFF_B32  5176     // 1
#define SMEM_FLOATS 5184

__global__ __launch_bounds__(256, 2) void barrier_policy_kernel(
    const float* __restrict__ x_g,
    const float* __restrict__ W1,  const float* __restrict__ b1,
    const float* __restrict__ W21, const float* __restrict__ b21,
    const float* __restrict__ W22, const float* __restrict__ b22,
    const float* __restrict__ W31, const float* __restrict__ b31,
    const float* __restrict__ W32, const float* __restrict__ b32,
    const float* __restrict__ Amat, const float* __restrict__ Gmat,
    const float* __restrict__ mean, const float* __restrict__ std_,
    float* __restrict__ out, int B)
{
    __shared__ float smem[SMEM_FLOATS];
    const int tid = threadIdx.x;

    // ---- stage all weights/consts into LDS (once per block) ----
    for (int i = tid; i < 512;  i += 256) smem[OFF_W1  + i] = W1[i];
    for (int i = tid; i < 2048; i += 256) smem[OFF_W21 + i] = W21[i];
    for (int i = tid; i < 2048; i += 256) smem[OFF_W22 + i] = W22[i];
    if (tid < 256) smem[OFF_W31 + tid] = W31[tid];
    if (tid < 32)  smem[OFF_W32 + tid] = W32[tid];
    if (tid < 64)  smem[OFF_B1  + tid] = b1[tid];
    if (tid < 32)  smem[OFF_B21 + tid] = b21[tid];
    if (tid < 32)  smem[OFF_B22 + tid] = b22[tid];
    if (tid < 8)   smem[OFF_B31 + tid] = b31[tid];
    if (tid < 64)  smem[OFF_A   + tid] = Amat[tid];
    if (tid < 64)  smem[OFF_G   + tid] = Gmat[tid];
    if (tid < 8)   smem[OFF_MEAN+ tid] = mean[tid];
    if (tid < 8)   smem[OFF_STD + tid] = std_[tid];
    if (tid == 0)  smem[OFF_B32] = b32[0];
    __syncthreads();

    const int row = blockIdx.x * blockDim.x + tid;
    if (row >= B) return;

    const float* sW1  = &smem[OFF_W1];
    const float* sW21 = &smem[OFF_W21];
    const float* sW22 = &smem[OFF_W22];
    const float* sW31 = &smem[OFF_W31];
    const float* sW32 = &smem[OFF_W32];

    // ---- load x (vectorized, 32B/thread) ----
    float x[NN];
    {
        const float4* xv = reinterpret_cast<const float4*>(x_g + (size_t)row * NN);
        float4 a0 = xv[0], a1 = xv[1];
        x[0] = a0.x; x[1] = a0.y; x[2] = a0.z; x[3] = a0.w;
        x[4] = a1.x; x[5] = a1.y; x[6] = a1.z; x[7] = a1.w;
    }

    // ---- un-normalized state ----
    float x0[NN];
#pragma unroll
    for (int i = 0; i < NN; ++i) x0[i] = fmaf(x[i], smem[OFF_STD + i], smem[OFF_MEAN + i]);

    // =====================================================================
    // MLP in packed FP32 (v_pk_fma_f32); weights from LDS with compile-time
    // offsets (wave-uniform ds_read broadcast, no per-load address VALU).
    // Accumulation order identical to round-6 kernel (bitwise-same result).
    // =====================================================================
    v2f a21[NH2 / 2], a22[NH2 / 2];
#pragma unroll
    for (int j2 = 0; j2 < NH2 / 2; ++j2) {
        a21[j2] = *(const v2f*)&smem[OFF_B21 + 2 * j2];
        a22[j2] = *(const v2f*)&smem[OFF_B22 + 2 * j2];
    }

#pragma unroll
    for (int k2 = 0; k2 < NH1 / 2; ++k2) {
        // layer-1 pair: h[2k2], h[2k2+1]
        v2f acc = *(const v2f*)&smem[OFF_B1 + 2 * k2];
#pragma unroll
        for (int i = 0; i < NN; ++i) {
            const v2f w = *(const v2f*)(sW1 + i * NH1 + 2 * k2);
            const v2f xi = { x[i], x[i] };
            acc = __builtin_elementwise_fma(xi, w, acc);
        }
        const v2f zero2 = { 0.0f, 0.0f };
        const v2f h2 = __builtin_elementwise_max(acc, zero2);

        // layer-2 accumulate: h[2k2] (row 2k2), then h[2k2+1] (row 2k2+1)
        const v2f ha = h2.xx, hb = h2.yy;
        const v2f* w21a = (const v2f*)(sW21 + (2 * k2) * NH2);
        const v2f* w21b = (const v2f*)(sW21 + (2 * k2 + 1) * NH2);
        const v2f* w22a = (const v2f*)(sW22 + (2 * k2) * NH2);
        const v2f* w22b = (const v2f*)(sW22 + (2 * k2 + 1) * NH2);
#pragma unroll
        for (int j2 = 0; j2 < NH2 / 2; ++j2) {
            a21[j2] = __builtin_elementwise_fma(ha, w21a[j2], a21[j2]);
            a22[j2] = __builtin_elementwise_fma(ha, w22a[j2], a22[j2]);
        }
#pragma unroll
        for (int j2 = 0; j2 < NH2 / 2; ++j2) {
            a21[j2] = __builtin_elementwise_fma(hb, w21b[j2], a21[j2]);
            a22[j2] = __builtin_elementwise_fma(hb, w22b[j2], a22[j2]);
        }
    }
    {
        const v2f zero2 = { 0.0f, 0.0f };
#pragma unroll
        for (int j2 = 0; j2 < NH2 / 2; ++j2) {
            a21[j2] = __builtin_elementwise_max(a21[j2], zero2);
            a22[j2] = __builtin_elementwise_max(a22[j2], zero2);
        }
    }

    // ---- p-head: pack output pairs (4 v2f), serial over k ----
    v2f pv[MM / 2];
#pragma unroll
    for (int j2 = 0; j2 < MM / 2; ++j2) pv[j2] = *(const v2f*)&smem[OFF_B31 + 2 * j2];
#pragma unroll
    for (int k2 = 0; k2 < NH2 / 2; ++k2) {
        const v2f hka = a21[k2].xx, hkb = a21[k2].yy;
        const v2f* w31a = (const v2f*)(sW31 + (2 * k2) * MM);
        const v2f* w31b = (const v2f*)(sW31 + (2 * k2 + 1) * MM);
#pragma unroll
        for (int j2 = 0; j2 < MM / 2; ++j2)
            pv[j2] = __builtin_elementwise_fma(hka, w31a[j2], pv[j2]);
#pragma unroll
        for (int j2 = 0; j2 < MM / 2; ++j2)
            pv[j2] = __builtin_elementwise_fma(hkb, w31b[j2], pv[j2]);
    }

    // ---- alpha-head: scalar (preserves exact serial rounding) ----
    float s = smem[OFF_B32];
#pragma unroll
    for (int k2 = 0; k2 < NH2 / 2; ++k2) {
        s = fmaf(a22[k2].x, sW32[2 * k2], s);
        s = fmaf(a22[k2].y, sW32[2 * k2 + 1], s);
    }
    const float alphax = 4.0f / (1.0f + __expf(-s));

    // ---- barrier terms (scalar, small) ----
    float hx = 16.0f;
#pragma unroll
    for (int i = 0; i < NN; ++i) hx = fmaf(-x0[i], x0[i], hx);

    float dh[NN];
#pragma unroll
    for (int i = 0; i < NN; ++i) dh[i] = -2.0f * x0[i];

    float Lfhx = 0.0f;
#pragma unroll
    for (int i = 0; i < NN; ++i) {
        float fx = 0.0f;
#pragma unroll
        for (int k = 0; k < NN; ++k) fx = fmaf(smem[OFF_A + i * NN + k], x0[k], fx);
        Lfhx = fmaf(dh[i], fx, Lfhx);
    }

    float g[MM];
#pragma unroll
    for (int j = 0; j < MM; ++j) {
        float acc = 0.0f;
#pragma unroll
        for (int i = 0; i < NN; ++i) acc = fmaf(dh[i], smem[OFF_G + i * MM + j], acc);
        g[j] = acc;
    }

    const float c0 = fmaf(alphax, hx, Lfhx);

    // =====================================================================
    // QP via exact piecewise-linear root isolation — fully scalarized
    // (no arrays -> nothing demotes to scratch; round-3 lesson).
    // =====================================================================
#define DECL_PG(j) const float p##j = (j & 1) ? pv[j >> 1].y : pv[j >> 1].x; \
                   const float g##j = g[j];
    FOR8(DECL_PG)
#undef DECL_PG

    auto c_of = [&](float lam) -> float {
        float c = c0;
#define CTERM(j) { float u = fmaf(lam, g##j, -p##j);                  \
                   u = fminf(fmaxf(u, -1.0f), 1.0f);                  \
                   c = fmaf(g##j, u, c); }
        FOR8(CTERM)
#undef CTERM
        return c;
    };

    const bool viol = (c_of(0.0f) < 0.0f);

    const float BIGR = 3.0e38f;         // sentinel: no right bracket found
    float lamL = 0.0f, lamR = BIGR;
#define BP(j) {                                                        \
        const float rg = __builtin_amdgcn_rcpf(g##j);                  \
        const float bpa = (p##j - 1.0f) * rg;                          \
        const float bpb = (p##j + 1.0f) * rg;                          \
        const float ca = c_of(bpa);                                    \
        const float cb = c_of(bpb);                                    \
        lamL = (bpa > 0.0f && ca <  0.0f && bpa > lamL) ? bpa : lamL;  \
        lamR = (bpa > 0.0f && ca >= 0.0f && bpa < lamR) ? bpa : lamR;  \
        lamL = (bpb > 0.0f && cb <  0.0f && bpb > lamL) ? bpb : lamL;  \
        lamR = (bpb > 0.0f && cb >= 0.0f && bpb < lamR) ? bpb : lamR;  \
    }
    FOR8(BP)
#undef BP

    // lam_t strictly inside the root's segment (same segment the reference's
    // bisection lands in). Infeasible => classify at the capped bracket 2^40.
    const bool infeas = (lamR == BIGR);
    float lam_t = infeas ? 1.099511627776e12f : 0.5f * (lamL + lamR);
    lam_t = viol ? lam_t : 0.0f;

    // frozen active set -> closed-form lambda (exact KKT refinement, == ref)
    float denom = 0.0f, num = c0;
#define ASET(j)                                                        \
    const float ur##j = fmaf(lam_t, g##j, -p##j);                      \
    const bool lo##j = (ur##j <= -1.0f);                               \
    const bool hi##j = (ur##j >=  1.0f);                               \
    denom += (!(lo##j || hi##j)) ? g##j * g##j : 0.0f;                 \
    num   += lo##j ? -g##j : (hi##j ? g##j : -g##j * p##j);
    FOR8(ASET)
#undef ASET

    const float lam = viol ? (-num / (denom + 1e-12f)) : 0.0f;

#define UOUT(j) const float uo##j =                                    \
    lo##j ? -1.0f : (hi##j ? 1.0f : fmaf(lam, g##j, -p##j));
    FOR8(UOUT)
#undef UOUT

    // ---- store (vectorized) ----
    float4* ov = reinterpret_cast<float4*>(out + (size_t)row * MM);
    ov[0] = make_float4(uo0, uo1, uo2, uo3);
    ov[1] = make_float4(uo4, uo5, uo6, uo7);
}

extern "C" void kernel_launch(void* const* d_in, const int* in_sizes, int n_in,
                              void* d_out, int out_size, void* d_ws, size_t ws_size,
                              hipStream_t stream) {
    const float* x    = (const float*)d_in[0];
    const float* W1   = (const float*)d_in[1];
    const float* b1   = (const float*)d_in[2];
    const float* W21  = (const float*)d_in[3];
    const float* b21  = (const float*)d_in[4];
    const float* W22  = (const float*)d_in[5];
    const float* b22  = (const float*)d_in[6];
    const float* W31  = (const float*)d_in[7];
    const float* b31  = (const float*)d_in[8];
    const float* W32  = (const float*)d_in[9];
    const float* b32  = (const float*)d_in[10];
    const float* Amat = (const float*)d_in[11];
    const float* Gmat = (const float*)d_in[12];
    const float* mean = (const float*)d_in[13];
    const float* std_ = (const float*)d_in[14];

    const int B = in_sizes[0] / NN;
    const int block = 256;
    const int grid = (B + block - 1) / block;

    barrier_policy_kernel<<<grid, block, 0, stream>>>(
        x, W1, b1, W21, b21, W22, b22, W31, b31, W32, b32,
        Amat, Gmat, mean, std_, (float*)d_out, B);
}